// Round 15
// baseline (197.075 us; speedup 1.0000x reference)
//
#include <hip/hip_runtime.h>
#include <hip/hip_bf16.h>
#include <math.h>

// Problem constants: N=4096 nodes, K=15 neighbors, D=64, IN=5, H=256 hidden, B=32 batch
#define NN 4096
#define KK 15
#define DD 64
#define HH 256
#define BB 32

typedef __attribute__((ext_vector_type(8))) short s16x8;   // 8 bf16 (MFMA A/B frag)
typedef __attribute__((ext_vector_type(4))) float f32x4;   // MFMA C/D frag

__device__ __forceinline__ float wave_reduce_sum(float v) {
  #pragma unroll
  for (int off = 1; off < 64; off <<= 1) v += __shfl_xor(v, off);
  return v;
}

__device__ __forceinline__ short f2bf(float f) {
  __hip_bfloat16 h = __float2bfloat16(f);
  return *reinterpret_cast<short*>(&h);
}
__device__ __forceinline__ float bf2f(short s) {
  unsigned u = ((unsigned)(unsigned short)s) << 16;
  return __uint_as_float(u);
}

// ---------------------------------------------------------------------------
// Kernel 1 (fused front): three block roles:
//   [0, 32768)        xt/xi/xj: v = lin_w @ x[b][n]; xt[n][b][:] = x[b][n][:]
//   [32768, 32832)    w1 -> bf16
//   [32832, 33856)    prep: ne = emb/||emb||; e_i, e_j dots
__global__ __launch_bounds__(256) void front_kernel(
    const float* __restrict__ x, const float* __restrict__ lin_w,
    const float* __restrict__ att, float* __restrict__ xt,
    float* __restrict__ xi, float* __restrict__ xj,
    const float* __restrict__ w1, short* __restrict__ w1b,
    const float* __restrict__ emb, float* __restrict__ ne,
    float* __restrict__ ei, float* __restrict__ ej) {
  int bid = blockIdx.x;
  int t = threadIdx.x;
  if (bid >= NN * BB / 4 + 64) {           // prep role
    int gid = (bid - (NN * BB / 4 + 64)) * 256 + t;
    int n = gid >> 6, lane = gid & 63;
    float v = emb[(size_t)n * DD + lane];
    float s2  = wave_reduce_sum(v * v);
    float sei = wave_reduce_sum(v * att[lane]);
    float sej = wave_reduce_sum(v * att[128 + lane]);
    ne[(size_t)n * DD + lane] = v / (sqrtf(s2) + 1e-8f);
    if (lane == 0) { ei[n] = sei; ej[n] = sej; }
    return;
  }
  if (bid >= NN * BB / 4) {                // w1cvt role
    int i = (bid - NN * BB / 4) * 256 + t;
    w1b[i] = f2bf(w1[i]);
    return;
  }
  int gid = bid * 256 + t;                 // xt role
  int pair = gid >> 6, lane = gid & 63;
  int n = pair >> 5, b = pair & 31;
  const float* xp = x + ((size_t)b * NN + n) * 5;
  const float* wp = lin_w + lane * 5;
  float v = 0.f;
  #pragma unroll
  for (int i = 0; i < 5; i++) v += xp[i] * wp[i];
  if (lane < 5) xt[(size_t)pair * 5 + lane] = xp[lane];  // node-major transpose of x
  float si = wave_reduce_sum(v * att[64 + lane]);
  float sj = wave_reduce_sum(v * att[192 + lane]);
  if (lane == 0) { xi[pair] = si; xj[pair] = sj; }
}

// ---------------------------------------------------------------------------
// Kernel 2: sim tile GEMM (fp32 — selection must stay fp32-exact)
__global__ __launch_bounds__(256) void sim_kernel(
    const float* __restrict__ ne, float* __restrict__ sim) {
  __shared__ float As[DD][68];
  __shared__ float Bs[DD][68];
  int t = threadIdx.x;
  int brow = blockIdx.y * 64;
  int bcol = blockIdx.x * 64;
  int lr = t >> 2, ldc = (t & 3) * 16;
  const float* pa = ne + (size_t)(brow + lr) * DD + ldc;
  const float* pb = ne + (size_t)(bcol + lr) * DD + ldc;
  #pragma unroll
  for (int j = 0; j < 16; j += 4) {
    float4 a = *(const float4*)(pa + j);
    float4 b = *(const float4*)(pb + j);
    float av[4] = {a.x, a.y, a.z, a.w};
    float bv[4] = {b.x, b.y, b.z, b.w};
    #pragma unroll
    for (int q = 0; q < 4; q++) {
      As[ldc + j + q][lr] = av[q];
      Bs[ldc + j + q][lr] = bv[q];
    }
  }
  __syncthreads();
  int tr = t >> 4, tc = t & 15;
  float acc[4][4] = {};
  #pragma unroll 16
  for (int k = 0; k < DD; k++) {
    float4 a = *(const float4*)&As[k][tr * 4];
    float4 b = *(const float4*)&Bs[k][tc * 4];
    float ar[4] = {a.x, a.y, a.z, a.w};
    float br[4] = {b.x, b.y, b.z, b.w};
    #pragma unroll
    for (int i = 0; i < 4; i++)
      #pragma unroll
      for (int j = 0; j < 4; j++)
        acc[i][j] += ar[i] * br[j];
  }
  int grow = brow + tr * 4;
  #pragma unroll
  for (int i = 0; i < 4; i++) {
    float4 o = {acc[i][0], acc[i][1], acc[i][2], acc[i][3]};
    *(float4*)(sim + (size_t)(grow + i) * NN + bcol + tc * 4) = o;
  }
}

// ---------------------------------------------------------------------------
// Kernel 3: EXACT top-15 per row via threshold selection (round-11, passing).
__global__ __launch_bounds__(256) void topk_kernel(
    const float* __restrict__ sim, int* __restrict__ src) {
  int t = threadIdx.x;
  int n = blockIdx.x;
  const float* row = sim + (size_t)n * NN;

  __shared__ __align__(16) unsigned cand[64];
  __shared__ unsigned s_thr;
  __shared__ int s_cgt, s_cnt, s_tie_cnt;
  __shared__ int s_tie[64];
  if (t == 0) { s_cnt = 0; s_tie_cnt = 0; }

  unsigned k0[16];
  #pragma unroll
  for (int c = 0; c < 4; c++) {
    float4 f = *(const float4*)(row + c * 1024 + t * 4);
    float fv[4] = {f.x, f.y, f.z, f.w};
    #pragma unroll
    for (int e = 0; e < 4; e++) {
      unsigned u = __float_as_uint(fv[e]);
      k0[c * 4 + e] = u ^ ((unsigned)(((int)u) >> 31) | 0x80000000u);  // exact
    }
  }
  unsigned s[16];
  #pragma unroll
  for (int i = 0; i < 16; i++) s[i] = k0[i];

  // bitonic sort-16 descending
  #pragma unroll
  for (int k = 2; k <= 16; k <<= 1) {
    #pragma unroll
    for (int j = k >> 1; j > 0; j >>= 1) {
      #pragma unroll
      for (int i = 0; i < 16; i++) {
        int ixj = i ^ j;
        if (ixj > i) {
          unsigned a = s[i], b = s[ixj];
          unsigned mx = (a > b) ? a : b;
          unsigned mn = (a > b) ? b : a;
          if ((i & k) == 0) { s[i] = mx; s[ixj] = mn; }
          else              { s[i] = mn; s[ixj] = mx; }
        }
      }
    }
  }

#define MERGE_ROUND(EXPR)                                                    \
  {                                                                          \
    unsigned p[16];                                                          \
    _Pragma("unroll")                                                        \
    for (int i = 0; i < 16; i++) { unsigned x = s[i]; p[i] = (unsigned)(EXPR); } \
    unsigned m[16];                                                          \
    _Pragma("unroll")                                                        \
    for (int i = 0; i < 16; i++) {                                           \
      unsigned q = p[15 - i];                                                \
      m[i] = (s[i] > q) ? s[i] : q;                                          \
    }                                                                        \
    _Pragma("unroll")                                                        \
    for (int j = 8; j > 0; j >>= 1) {                                        \
      _Pragma("unroll")                                                      \
      for (int i = 0; i < 16; i++) {                                         \
        int ixj = i ^ j;                                                     \
        if (ixj > i) {                                                       \
          unsigned a = m[i], b = m[ixj];                                     \
          m[i]   = (a > b) ? a : b;                                          \
          m[ixj] = (a > b) ? b : a;                                          \
        }                                                                    \
      }                                                                      \
    }                                                                        \
    _Pragma("unroll")                                                        \
    for (int i = 0; i < 16; i++) s[i] = m[i];                                \
  }

  MERGE_ROUND(__builtin_amdgcn_update_dpp(0, (int)x, 0xB1, 0xF, 0xF, true))  // xor1
  MERGE_ROUND(__builtin_amdgcn_update_dpp(0, (int)x, 0x4E, 0xF, 0xF, true))  // xor2
  MERGE_ROUND(__shfl_xor((int)x, 4))
  MERGE_ROUND(__shfl_xor((int)x, 8))
  MERGE_ROUND(__shfl_xor((int)x, 16))
  MERGE_ROUND(__shfl_xor((int)x, 32))
#undef MERGE_ROUND

  int wv = t >> 6, l = t & 63;
  if (l == 0) {
    #pragma unroll
    for (int i = 0; i < 16; i++) cand[wv * 16 + i] = s[i];
  }
  __syncthreads();

  if (t < 64) {
    unsigned my = cand[t];
    int r = 0, eq = 0;
    #pragma unroll
    for (int i = 0; i < 64; i += 4) {
      uint4 c4 = *(const uint4*)&cand[i];
      r  += (c4.x > my) + (c4.y > my) + (c4.z > my) + (c4.w > my);
      eq += (c4.x == my) + (c4.y == my) + (c4.z == my) + (c4.w == my);
    }
    if (r <= 14 && r + eq >= 15) { s_thr = my; s_cgt = r; }  // benign multi-write
  }
  __syncthreads();

  unsigned thr = s_thr;
  #pragma unroll
  for (int q = 0; q < 16; q++) {
    unsigned kv = k0[q];
    if (kv > thr) {
      int slot = atomicAdd(&s_cnt, 1);
      src[n * KK + slot] = ((q >> 2) << 10) + t * 4 + (q & 3);
    } else if (kv == thr) {
      int ts = atomicAdd(&s_tie_cnt, 1);
      if (ts < 64) s_tie[ts] = ((q >> 2) << 10) + t * 4 + (q & 3);
    }
  }
  __syncthreads();
  if (t == 0) {
    int cgt = s_cgt;
    int tn = s_tie_cnt; if (tn > 64) tn = 64;
    for (int slot = cgt; slot < KK; slot++) {
      int best = 1 << 30, bi = 0;
      for (int i = 0; i < tn; i++)
        if (s_tie[i] < best) { best = s_tie[i]; bi = i; }
      src[n * KK + slot] = best;
      s_tie[bi] = 1 << 30;
    }
  }
}

// ---------------------------------------------------------------------------
// Kernel 4 (fused gcn+mlp), one block per node n.
// Round-15: rank-5 gather. gcn[b][d] = sum_i lin_w[d][i] * xg[b][i] with
// xg[b][i] = sum_k alpha[k][b] * x[b][src_k][i] — gathers 20B/neighbor (xt,
// 2.6MB L2-resident) instead of 128B xh rows. Exact same math reordered in
// fp32 (removes xh's bf16 rounding). Phase B (MFMA MLP) unchanged.
__global__ __launch_bounds__(256) void gcn_mlp_kernel(
    const int* __restrict__ src, const float* __restrict__ ei,
    const float* __restrict__ ej, const float* __restrict__ xi,
    const float* __restrict__ xj, const float* __restrict__ xt,
    const float* __restrict__ lin_w, const float* __restrict__ emb,
    const short* __restrict__ w1b, const float* __restrict__ b1,
    const float* __restrict__ w2, const float* __restrict__ b2,
    float* __restrict__ y) {
  int n = blockIdx.x, t = threadIdx.x;
  int w = t >> 6, l = t & 63;
  int lm = l & 15, lk = l >> 4;

  __shared__ int s_src[KK];
  __shared__ float s_ej[KK], s_xi[BB], s_alpha[KK][BB], s_emb[DD];
  __shared__ float s_xt[KK][BB * 5];   // 9600 B
  __shared__ float s_w[DD * 5];        // 1280 B
  __shared__ float s_xg[BB * 5];       // 640 B
  __shared__ __align__(16) short out_lds[256 * 8];  // 4 KB, swizzled 16B slots
  __shared__ float part[4][32];

  if (t < KK) { int m = src[n * KK + t]; s_src[t] = m; s_ej[t] = ej[m]; }
  if (t >= 32 && t < 64) s_xi[t - 32] = xi[n * BB + (t - 32)];
  if (t >= 64 && t < 128) s_emb[t - 64] = emb[(size_t)n * DD + (t - 64)];
  for (int idx = t; idx < DD * 5; idx += 256) s_w[idx] = lin_w[idx];
  __syncthreads();

  // gather 15 xt rows (640B contiguous each, L2-resident) into LDS
  for (int idx = t; idx < KK * 160; idx += 256) {
    int k = idx / 160, r = idx - k * 160;
    s_xt[k][r] = xt[(size_t)s_src[k] * 160 + r];
  }
  // alpha logits
  for (int idx = t; idx < KK * BB; idx += 256) {
    int k = idx >> 5, bb = idx & 31;
    float a = ei[n] + s_xi[bb] + s_ej[k] + xj[s_src[k] * BB + bb];
    a = (a > 0.f) ? a : 0.2f * a;
    s_alpha[k][bb] = a;
  }
  __syncthreads();
  if (t < BB) {
    float p[KK];
    float mx = -1e30f;
    #pragma unroll
    for (int k = 0; k < KK; k++) mx = fmaxf(mx, s_alpha[k][t]);
    float s = 0.f;
    #pragma unroll
    for (int k = 0; k < KK; k++) { p[k] = expf(s_alpha[k][t] - mx); s += p[k]; }
    float inv = 1.f / s;
    #pragma unroll
    for (int k = 0; k < KK; k++) s_alpha[k][t] = p[k] * inv;
  }
  __syncthreads();
  // xg[b][i] = sum_k alpha[k][b] * xt[src_k][b][i]
  if (t < BB * 5) {
    int b = t / 5, i = t - (t / 5) * 5;
    float s = 0.f;
    #pragma unroll
    for (int k = 0; k < KK; k++) s += s_alpha[k][b] * s_xt[k][b * 5 + i];
    s_xg[t] = s;
  }
  __syncthreads();
  // out[b][d] = (sum_i w[d][i]*xg[b][i]) * emb[n][d], pack bf16 swizzled
  {
    int b = t >> 3, d0 = (t & 7) * 8;
    float xgv[5];
    #pragma unroll
    for (int i = 0; i < 5; i++) xgv[i] = s_xg[b * 5 + i];
    s16x8 o;
    #pragma unroll
    for (int j = 0; j < 8; j++) {
      int d = d0 + j;
      float acc = 0.f;
      #pragma unroll
      for (int i = 0; i < 5; i++) acc += s_w[d * 5 + i] * xgv[i];
      o[j] = f2bf(acc * s_emb[d]);
    }
    int slot = (t & ~7) | ((t & 7) ^ ((t >> 3) & 7));
    *(s16x8*)&out_lds[slot * 8] = o;
  }
  __syncthreads();

  // B-operand fragments (w1b is L2-resident, 32 KB): wave w owns cols 64w..64w+63
  s16x8 bfrag[4][2];
  float b1v[4], w2v[4];
  #pragma unroll
  for (int j = 0; j < 4; j++) {
    int c = 64 * w + 16 * j + lm;
    #pragma unroll
    for (int s = 0; s < 2; s++)
      bfrag[j][s] = *(const s16x8*)(w1b + (size_t)c * DD + s * 32 + lk * 8);
    b1v[j] = b1[c];
    w2v[j] = w2[c];
  }
  float b2v = b2[0];

  // Phase B: A(32x64) @ w1^T. A-frag lane l, row-tile i, k-half s:
  //   row b = 16i+lm, k-bytes owned by phase-A thread t' = b*8 + (4s+lk)
  f32x4 acc2[2][4] = {};
  #pragma unroll
  for (int s = 0; s < 2; s++) {
    s16x8 afrag[2];
    #pragma unroll
    for (int i = 0; i < 2; i++) {
      int bb = 16 * i + lm;
      int jj = 4 * s + lk;
      int sl = bb * 8 + (jj ^ (bb & 7));
      afrag[i] = *(const s16x8*)&out_lds[sl * 8];
    }
    #pragma unroll
    for (int i = 0; i < 2; i++)
      #pragma unroll
      for (int j = 0; j < 4; j++)
        acc2[i][j] = __builtin_amdgcn_mfma_f32_16x16x32_bf16(
            afrag[i], bfrag[j][s], acc2[i][j], 0, 0, 0);
  }
  // epilogue: relu + w2-weighted col sum, reduce over 16 col-lanes (lm)
  float p[2][4];
  #pragma unroll
  for (int i = 0; i < 2; i++)
    #pragma unroll
    for (int r = 0; r < 4; r++) {
      float sum = 0.f;
      #pragma unroll
      for (int j = 0; j < 4; j++) {
        float h = acc2[i][j][r] + b1v[j];
        h = fmaxf(h, 0.f);
        sum += h * w2v[j];
      }
      p[i][r] = sum;
    }
  #pragma unroll
  for (int off = 1; off < 16; off <<= 1)
    #pragma unroll
    for (int i = 0; i < 2; i++)
      #pragma unroll
      for (int r = 0; r < 4; r++)
        p[i][r] += __shfl_xor(p[i][r], off);
  if (lm == 0) {
    #pragma unroll
    for (int i = 0; i < 2; i++)
      #pragma unroll
      for (int r = 0; r < 4; r++)
        part[w][16 * i + 4 * lk + r] = p[i][r];
  }
  __syncthreads();
  if (t < BB)
    y[(size_t)t * NN + n] = b2v + part[0][t] + part[1][t] + part[2][t] + part[3][t];
}

// ---------------------------------------------------------------------------
extern "C" void kernel_launch(void* const* d_in, const int* in_sizes, int n_in,
                              void* d_out, int out_size, void* d_ws, size_t ws_size,
                              hipStream_t stream) {
  const float* x     = (const float*)d_in[0];
  const float* emb   = (const float*)d_in[1];
  const float* lin_w = (const float*)d_in[2];
  const float* att   = (const float*)d_in[3];
  const float* w1    = (const float*)d_in[4];
  const float* b1    = (const float*)d_in[5];
  const float* w2    = (const float*)d_in[6];
  const float* b2    = (const float*)d_in[7];
  float* y = (float*)d_out;

  char* ws = (char*)d_ws;
  // workspace layout (256B aligned), peak ~72 MB
  float* ne     = (float*)(ws + 0);          // N*D f32      = 1,048,576 B
  float* ei     = (float*)(ws + 1048576);    // N f32        =    16,384 B
  float* ej     = (float*)(ws + 1064960);    // N f32        =    16,384 B
  float* xi     = (float*)(ws + 1081344);    // N*B f32      =   524,288 B
  float* xj     = (float*)(ws + 1605632);    // N*B f32      =   524,288 B
  int*   srcbuf = (int*)  (ws + 2129920);    // N*K i32      =   245,760 B
  short* w1b    = (short*)(ws + 2375680);    // H*D bf16     =    32,768 B
  float* xt     = (float*)(ws + 2408448);    // N*B*5 f32    = 2,621,440 B
  float* simbuf = (float*)(ws + 5029888);    // N*N f32      = 67,108,864 B

  front_kernel<<<NN * BB / 4 + 64 + NN / 4, 256, 0, stream>>>(
      x, lin_w, att, xt, xi, xj, w1, w1b, emb, ne, ei, ej);

  dim3 g(64, 64);
  sim_kernel<<<g, 256, 0, stream>>>(ne, simbuf);
  topk_kernel<<<NN, 256, 0, stream>>>(simbuf, srcbuf);

  gcn_mlp_kernel<<<NN, 256, 0, stream>>>(srcbuf, ei, ej, xi, xj, xt, lin_w,
                                         emb, w1b, b1, w2, b2, y);
}

// Round 16
// 193.166 us; speedup vs baseline: 1.0202x; 1.0202x over previous
//
#include <hip/hip_runtime.h>
#include <hip/hip_bf16.h>
#include <math.h>

// Problem constants: N=4096 nodes, K=15 neighbors, D=64, IN=5, H=256 hidden, B=32 batch
#define NN 4096
#define KK 15
#define DD 64
#define HH 256
#define BB 32

typedef __attribute__((ext_vector_type(8))) short s16x8;   // 8 bf16 (MFMA A/B frag)
typedef __attribute__((ext_vector_type(4))) float f32x4;   // MFMA C/D frag

__device__ __forceinline__ float wave_reduce_sum(float v) {
  #pragma unroll
  for (int off = 1; off < 64; off <<= 1) v += __shfl_xor(v, off);
  return v;
}

__device__ __forceinline__ short f2bf(float f) {
  __hip_bfloat16 h = __float2bfloat16(f);
  return *reinterpret_cast<short*>(&h);
}

// ---------------------------------------------------------------------------
// Kernel 1 (fused front): three block roles:
//   [0, 32768)        xt/xi/xj: v = lin_w @ x[b][n]; xt[n][b][:] = x[b][n][:]
//   [32768, 32832)    w1 -> bf16
//   [32832, 33856)    prep: ne = emb/||emb||; e_i, e_j dots
__global__ __launch_bounds__(256) void front_kernel(
    const float* __restrict__ x, const float* __restrict__ lin_w,
    const float* __restrict__ att, float* __restrict__ xt,
    float* __restrict__ xi, float* __restrict__ xj,
    const float* __restrict__ w1, short* __restrict__ w1b,
    const float* __restrict__ emb, float* __restrict__ ne,
    float* __restrict__ ei, float* __restrict__ ej) {
  int bid = blockIdx.x;
  int t = threadIdx.x;
  if (bid >= NN * BB / 4 + 64) {           // prep role
    int gid = (bid - (NN * BB / 4 + 64)) * 256 + t;
    int n = gid >> 6, lane = gid & 63;
    float v = emb[(size_t)n * DD + lane];
    float s2  = wave_reduce_sum(v * v);
    float sei = wave_reduce_sum(v * att[lane]);
    float sej = wave_reduce_sum(v * att[128 + lane]);
    ne[(size_t)n * DD + lane] = v / (sqrtf(s2) + 1e-8f);
    if (lane == 0) { ei[n] = sei; ej[n] = sej; }
    return;
  }
  if (bid >= NN * BB / 4) {                // w1cvt role
    int i = (bid - NN * BB / 4) * 256 + t;
    w1b[i] = f2bf(w1[i]);
    return;
  }
  int gid = bid * 256 + t;                 // xt role
  int pair = gid >> 6, lane = gid & 63;
  int n = pair >> 5, b = pair & 31;
  const float* xp = x + ((size_t)b * NN + n) * 5;
  const float* wp = lin_w + lane * 5;
  float v = 0.f;
  #pragma unroll
  for (int i = 0; i < 5; i++) v += xp[i] * wp[i];
  if (lane < 5) xt[(size_t)pair * 5 + lane] = xp[lane];  // node-major transpose of x
  float si = wave_reduce_sum(v * att[64 + lane]);
  float sj = wave_reduce_sum(v * att[192 + lane]);
  if (lane == 0) { xi[pair] = si; xj[pair] = sj; }
}

// ---------------------------------------------------------------------------
// Kernel 2: sim tile GEMM (fp32 — selection must stay fp32-exact)
__global__ __launch_bounds__(256) void sim_kernel(
    const float* __restrict__ ne, float* __restrict__ sim) {
  __shared__ float As[DD][68];
  __shared__ float Bs[DD][68];
  int t = threadIdx.x;
  int brow = blockIdx.y * 64;
  int bcol = blockIdx.x * 64;
  int lr = t >> 2, ldc = (t & 3) * 16;
  const float* pa = ne + (size_t)(brow + lr) * DD + ldc;
  const float* pb = ne + (size_t)(bcol + lr) * DD + ldc;
  #pragma unroll
  for (int j = 0; j < 16; j += 4) {
    float4 a = *(const float4*)(pa + j);
    float4 b = *(const float4*)(pb + j);
    float av[4] = {a.x, a.y, a.z, a.w};
    float bv[4] = {b.x, b.y, b.z, b.w};
    #pragma unroll
    for (int q = 0; q < 4; q++) {
      As[ldc + j + q][lr] = av[q];
      Bs[ldc + j + q][lr] = bv[q];
    }
  }
  __syncthreads();
  int tr = t >> 4, tc = t & 15;
  float acc[4][4] = {};
  #pragma unroll 16
  for (int k = 0; k < DD; k++) {
    float4 a = *(const float4*)&As[k][tr * 4];
    float4 b = *(const float4*)&Bs[k][tc * 4];
    float ar[4] = {a.x, a.y, a.z, a.w};
    float br[4] = {b.x, b.y, b.z, b.w};
    #pragma unroll
    for (int i = 0; i < 4; i++)
      #pragma unroll
      for (int j = 0; j < 4; j++)
        acc[i][j] += ar[i] * br[j];
  }
  int grow = brow + tr * 4;
  #pragma unroll
  for (int i = 0; i < 4; i++) {
    float4 o = {acc[i][0], acc[i][1], acc[i][2], acc[i][3]};
    *(float4*)(sim + (size_t)(grow + i) * NN + bcol + tc * 4) = o;
  }
}

// ---------------------------------------------------------------------------
// Kernel 3: EXACT top-15 per row via threshold selection (round-11, passing).
__global__ __launch_bounds__(256) void topk_kernel(
    const float* __restrict__ sim, int* __restrict__ src) {
  int t = threadIdx.x;
  int n = blockIdx.x;
  const float* row = sim + (size_t)n * NN;

  __shared__ __align__(16) unsigned cand[64];
  __shared__ unsigned s_thr;
  __shared__ int s_cgt, s_cnt, s_tie_cnt;
  __shared__ int s_tie[64];
  if (t == 0) { s_cnt = 0; s_tie_cnt = 0; }

  unsigned k0[16];
  #pragma unroll
  for (int c = 0; c < 4; c++) {
    float4 f = *(const float4*)(row + c * 1024 + t * 4);
    float fv[4] = {f.x, f.y, f.z, f.w};
    #pragma unroll
    for (int e = 0; e < 4; e++) {
      unsigned u = __float_as_uint(fv[e]);
      k0[c * 4 + e] = u ^ ((unsigned)(((int)u) >> 31) | 0x80000000u);  // exact
    }
  }
  unsigned s[16];
  #pragma unroll
  for (int i = 0; i < 16; i++) s[i] = k0[i];

  // bitonic sort-16 descending
  #pragma unroll
  for (int k = 2; k <= 16; k <<= 1) {
    #pragma unroll
    for (int j = k >> 1; j > 0; j >>= 1) {
      #pragma unroll
      for (int i = 0; i < 16; i++) {
        int ixj = i ^ j;
        if (ixj > i) {
          unsigned a = s[i], b = s[ixj];
          unsigned mx = (a > b) ? a : b;
          unsigned mn = (a > b) ? b : a;
          if ((i & k) == 0) { s[i] = mx; s[ixj] = mn; }
          else              { s[i] = mn; s[ixj] = mx; }
        }
      }
    }
  }

#define MERGE_ROUND(EXPR)                                                    \
  {                                                                          \
    unsigned p[16];                                                          \
    _Pragma("unroll")                                                        \
    for (int i = 0; i < 16; i++) { unsigned x = s[i]; p[i] = (unsigned)(EXPR); } \
    unsigned m[16];                                                          \
    _Pragma("unroll")                                                        \
    for (int i = 0; i < 16; i++) {                                           \
      unsigned q = p[15 - i];                                                \
      m[i] = (s[i] > q) ? s[i] : q;                                          \
    }                                                                        \
    _Pragma("unroll")                                                        \
    for (int j = 8; j > 0; j >>= 1) {                                        \
      _Pragma("unroll")                                                      \
      for (int i = 0; i < 16; i++) {                                         \
        int ixj = i ^ j;                                                     \
        if (ixj > i) {                                                       \
          unsigned a = m[i], b = m[ixj];                                     \
          m[i]   = (a > b) ? a : b;                                          \
          m[ixj] = (a > b) ? b : a;                                          \
        }                                                                    \
      }                                                                      \
    }                                                                        \
    _Pragma("unroll")                                                        \
    for (int i = 0; i < 16; i++) s[i] = m[i];                                \
  }

  MERGE_ROUND(__builtin_amdgcn_update_dpp(0, (int)x, 0xB1, 0xF, 0xF, true))  // xor1
  MERGE_ROUND(__builtin_amdgcn_update_dpp(0, (int)x, 0x4E, 0xF, 0xF, true))  // xor2
  MERGE_ROUND(__shfl_xor((int)x, 4))
  MERGE_ROUND(__shfl_xor((int)x, 8))
  MERGE_ROUND(__shfl_xor((int)x, 16))
  MERGE_ROUND(__shfl_xor((int)x, 32))
#undef MERGE_ROUND

  int wv = t >> 6, l = t & 63;
  if (l == 0) {
    #pragma unroll
    for (int i = 0; i < 16; i++) cand[wv * 16 + i] = s[i];
  }
  __syncthreads();

  if (t < 64) {
    unsigned my = cand[t];
    int r = 0, eq = 0;
    #pragma unroll
    for (int i = 0; i < 64; i += 4) {
      uint4 c4 = *(const uint4*)&cand[i];
      r  += (c4.x > my) + (c4.y > my) + (c4.z > my) + (c4.w > my);
      eq += (c4.x == my) + (c4.y == my) + (c4.z == my) + (c4.w == my);
    }
    if (r <= 14 && r + eq >= 15) { s_thr = my; s_cgt = r; }  // benign multi-write
  }
  __syncthreads();

  unsigned thr = s_thr;
  #pragma unroll
  for (int q = 0; q < 16; q++) {
    unsigned kv = k0[q];
    if (kv > thr) {
      int slot = atomicAdd(&s_cnt, 1);
      src[n * KK + slot] = ((q >> 2) << 10) + t * 4 + (q & 3);
    } else if (kv == thr) {
      int ts = atomicAdd(&s_tie_cnt, 1);
      if (ts < 64) s_tie[ts] = ((q >> 2) << 10) + t * 4 + (q & 3);
    }
  }
  __syncthreads();
  if (t == 0) {
    int cgt = s_cgt;
    int tn = s_tie_cnt; if (tn > 64) tn = 64;
    for (int slot = cgt; slot < KK; slot++) {
      int best = 1 << 30, bi = 0;
      for (int i = 0; i < tn; i++)
        if (s_tie[i] < best) { best = s_tie[i]; bi = i; }
      src[n * KK + slot] = best;
      s_tie[bi] = 1 << 30;
    }
  }
}

// ---------------------------------------------------------------------------
// Kernel 4 (fused gcn+mlp), FOUR nodes per block (grid 1024 = 4 blocks/CU,
// ~30KB LDS -> all blocks co-resident; barriers amortized 4x). Wave w owns
// node w's entire 32x256 MLP in phase B (no cross-wave reduce). xt gathers
// prefetched into registers right after s_src (round-14 lesson).
__global__ __launch_bounds__(256) void gcn_mlp_kernel(
    const int* __restrict__ src, const float* __restrict__ ei,
    const float* __restrict__ ej, const float* __restrict__ xi,
    const float* __restrict__ xj, const float* __restrict__ xt,
    const float* __restrict__ lin_w, const float* __restrict__ emb,
    const short* __restrict__ w1b, const float* __restrict__ b1,
    const float* __restrict__ w2, const float* __restrict__ b2,
    float* __restrict__ y) {
  int n0 = blockIdx.x * 4, t = threadIdx.x;
  int w = t >> 6, l = t & 63;
  int lm = l & 15, lk = l >> 4;

  __shared__ int   s_src[4][KK];
  __shared__ float s_ej[4][KK], s_xi[4][BB], s_ei[4];
  __shared__ float s_alpha[4][KK][BB];
  __shared__ float s_emb[4][DD];
  __shared__ float s_w[DD * 5];
  __shared__ float s_xg[4][BB * 5];
  __shared__ __align__(16) short out_lds[4][256 * 8];  // 4x4KB swizzled

  // phase 1: head loads
  if (t < 4 * KK) {
    int g = t / KK, k = t - g * KK;
    int m = src[(n0 + g) * KK + k];
    s_src[g][k] = m; s_ej[g][k] = ej[m];
  }
  if (t >= 64 && t < 192) {
    int g = (t - 64) >> 5, b = (t - 64) & 31;
    s_xi[g][b] = xi[(n0 + g) * BB + b];
  }
  if (t >= 192 && t < 196) s_ei[t - 192] = ei[n0 + (t - 192)];
  { int g = t >> 6, d = t & 63; s_emb[g][d] = emb[(size_t)(n0 + g) * DD + d]; }
  for (int idx = t; idx < DD * 5; idx += 256) s_w[idx] = lin_w[idx];
  __syncthreads();

  // prefetch all xt gathers (consumed in phase 4; latency hides under 2+3)
  float pf[3][KK];
  #pragma unroll
  for (int u = 0; u < 3; u++) {
    int idx = t + 256 * u;
    if (idx < 640) {
      int g = idx / 160, r = idx - g * 160;
      int b = r / 5, i = r - b * 5;
      #pragma unroll
      for (int k = 0; k < KK; k++)
        pf[u][k] = xt[(size_t)s_src[g][k] * 160 + b * 5 + i];
    }
  }

  // phase 2: alpha logits (1920 elems)
  for (int idx = t; idx < 4 * KK * BB; idx += 256) {
    int g = idx / (KK * BB), r = idx - g * (KK * BB);
    int k = r >> 5, b = r & 31;
    float a = s_ei[g] + s_xi[g][b] + s_ej[g][k] + xj[s_src[g][k] * BB + b];
    a = (a > 0.f) ? a : 0.2f * a;
    s_alpha[g][k][b] = a;
  }
  __syncthreads();

  // phase 3: softmax over k (128 threads: (g,b))
  if (t < 128) {
    int g = t >> 5, b = t & 31;
    float mx = -1e30f;
    #pragma unroll
    for (int k = 0; k < KK; k++) mx = fmaxf(mx, s_alpha[g][k][b]);
    float p[KK], s = 0.f;
    #pragma unroll
    for (int k = 0; k < KK; k++) { p[k] = expf(s_alpha[g][k][b] - mx); s += p[k]; }
    float inv = 1.f / s;
    #pragma unroll
    for (int k = 0; k < KK; k++) s_alpha[g][k][b] = p[k] * inv;
  }
  __syncthreads();

  // phase 4: xg[g][b][i] = sum_k alpha * pf
  #pragma unroll
  for (int u = 0; u < 3; u++) {
    int idx = t + 256 * u;
    if (idx < 640) {
      int g = idx / 160, r = idx - g * 160;
      int b = r / 5;
      float s = 0.f;
      #pragma unroll
      for (int k = 0; k < KK; k++) s += s_alpha[g][k][b] * pf[u][k];
      s_xg[g][r] = s;
    }
  }
  __syncthreads();

  // phase 5: out[g][b][d] = (sum_i w[d][i]*xg[g][b][i]) * emb, bf16 swizzled
  {
    int b = t >> 3, d0 = (t & 7) * 8;
    int slot = (t & ~7) | ((t & 7) ^ ((t >> 3) & 7));
    #pragma unroll
    for (int g = 0; g < 4; g++) {
      float xgv[5];
      #pragma unroll
      for (int i = 0; i < 5; i++) xgv[i] = s_xg[g][b * 5 + i];
      s16x8 o;
      #pragma unroll
      for (int j = 0; j < 8; j++) {
        int d = d0 + j;
        float acc = 0.f;
        #pragma unroll
        for (int i = 0; i < 5; i++) acc += s_w[d * 5 + i] * xgv[i];
        o[j] = f2bf(acc * s_emb[g][d]);
      }
      *(s16x8*)&out_lds[g][slot * 8] = o;
    }
  }
  __syncthreads();

  // phase 6: wave w = node w's 32x256 MLP; loop 4 col-quarters of w1b (L2-hot)
  s16x8 afrag[2][2];   // [s][i]: row bb=16i+lm, k-octet jj=4s+lk
  #pragma unroll
  for (int s = 0; s < 2; s++)
    #pragma unroll
    for (int i = 0; i < 2; i++) {
      int bb = 16 * i + lm, jj = 4 * s + lk;
      int sl = bb * 8 + (jj ^ (bb & 7));
      afrag[s][i] = *(const s16x8*)&out_lds[w][sl * 8];
    }
  float psum[2][4] = {};
  #pragma unroll
  for (int q = 0; q < 4; q++) {
    s16x8 bfrag[4][2];
    float b1v[4], w2v[4];
    #pragma unroll
    for (int j = 0; j < 4; j++) {
      int c = 64 * q + 16 * j + lm;
      #pragma unroll
      for (int s = 0; s < 2; s++)
        bfrag[j][s] = *(const s16x8*)(w1b + (size_t)c * DD + s * 32 + lk * 8);
      b1v[j] = b1[c]; w2v[j] = w2[c];
    }
    f32x4 acc2[2][4] = {};
    #pragma unroll
    for (int s = 0; s < 2; s++)
      #pragma unroll
      for (int i = 0; i < 2; i++)
        #pragma unroll
        for (int j = 0; j < 4; j++)
          acc2[i][j] = __builtin_amdgcn_mfma_f32_16x16x32_bf16(
              afrag[s][i], bfrag[j][s], acc2[i][j], 0, 0, 0);
    #pragma unroll
    for (int i = 0; i < 2; i++)
      #pragma unroll
      for (int r = 0; r < 4; r++) {
        float sum = 0.f;
        #pragma unroll
        for (int j = 0; j < 4; j++) {
          float h = acc2[i][j][r] + b1v[j];
          h = fmaxf(h, 0.f);
          sum += h * w2v[j];
        }
        psum[i][r] += sum;
      }
  }
  #pragma unroll
  for (int off = 1; off < 16; off <<= 1)
    #pragma unroll
    for (int i = 0; i < 2; i++)
      #pragma unroll
      for (int r = 0; r < 4; r++)
        psum[i][r] += __shfl_xor(psum[i][r], off);
  if (lm == 0) {
    float b2v = b2[0];
    #pragma unroll
    for (int i = 0; i < 2; i++)
      #pragma unroll
      for (int r = 0; r < 4; r++)
        y[(size_t)(16 * i + 4 * lk + r) * NN + n0 + w] = b2v + psum[i][r];
  }
}

// ---------------------------------------------------------------------------
extern "C" void kernel_launch(void* const* d_in, const int* in_sizes, int n_in,
                              void* d_out, int out_size, void* d_ws, size_t ws_size,
                              hipStream_t stream) {
  const float* x     = (const float*)d_in[0];
  const float* emb   = (const float*)d_in[1];
  const float* lin_w = (const float*)d_in[2];
  const float* att   = (const float*)d_in[3];
  const float* w1    = (const float*)d_in[4];
  const float* b1    = (const float*)d_in[5];
  const float* w2    = (const float*)d_in[6];
  const float* b2    = (const float*)d_in[7];
  float* y = (float*)d_out;

  char* ws = (char*)d_ws;
  // workspace layout (256B aligned), peak ~72 MB
  float* ne     = (float*)(ws + 0);          // N*D f32      = 1,048,576 B
  float* ei     = (float*)(ws + 1048576);    // N f32        =    16,384 B
  float* ej     = (float*)(ws + 1064960);    // N f32        =    16,384 B
  float* xi     = (float*)(ws + 1081344);    // N*B f32      =   524,288 B
  float* xj     = (float*)(ws + 1605632);    // N*B f32      =   524,288 B
  int*   srcbuf = (int*)  (ws + 2129920);    // N*K i32      =   245,760 B
  short* w1b    = (short*)(ws + 2375680);    // H*D bf16     =    32,768 B
  float* xt     = (float*)(ws + 2408448);    // N*B*5 f32    = 2,621,440 B
  float* simbuf = (float*)(ws + 5029888);    // N*N f32      = 67,108,864 B

  front_kernel<<<NN * BB / 4 + 64 + NN / 4, 256, 0, stream>>>(
      x, lin_w, att, xt, xi, xj, w1, w1b, emb, ne, ei, ej);

  dim3 g(64, 64);
  sim_kernel<<<g, 256, 0, stream>>>(ne, simbuf);
  topk_kernel<<<NN, 256, 0, stream>>>(simbuf, srcbuf);

  gcn_mlp_kernel<<<NN / 4, 256, 0, stream>>>(srcbuf, ei, ej, xi, xj, xt, lin_w,
                                             emb, w1b, b1, w2, b2, y);
}